// Round 11
// baseline (618.287 us; speedup 1.0000x reference)
//
#include <hip/hip_runtime.h>

typedef short bf16x8 __attribute__((ext_vector_type(8)));
typedef float f32x4  __attribute__((ext_vector_type(4)));
typedef unsigned short u16;

#define B_ 4
#define R_ 36
#define RP 48          // r padded to 3 m-tiles of 16
#define C_ 3
#define H_ 384
#define W_ 224
#define KS 64
#define OY 321         // conv-out rows needed
#define OX 161         // conv-out cols needed
#define HC 320
#define WC 160
#define LCOLS 128      // staged cols per WG
#define PITCH 120      // B rows per col: 64 + 56 (waves at 8w, +32 for 2nd y)
#define GR 3072        // u16 per A-granule: 2 planes x 48 r x 32 ky (6 KB)
#define BLKS_PER_BATCH 7200
#define EXP_BLKS_PER_BATCH 1800   // float4 tail: 1024 elems/block

__device__ __forceinline__ u16 bf16rtn(float v) {
    union { float f; unsigned u; } U; U.f = v;
    unsigned r = U.u + 0x7fffu + ((U.u >> 16) & 1u);
    return (u16)(r >> 16);
}
__device__ __forceinline__ float bf16tof(u16 h) {
    union { float f; unsigned u; } U; U.u = ((unsigned)h) << 16; return U.f;
}

__device__ __forceinline__ float wave_max(float v) {
    #pragma unroll
    for (int off = 32; off > 0; off >>= 1) v = fmaxf(v, __shfl_down(v, off, 64));
    return v;
}
__device__ __forceinline__ float wave_sum(float v) {
    #pragma unroll
    for (int off = 32; off > 0; off >>= 1) v += __shfl_down(v, off, 64);
    return v;
}

// Weights -> per-(b,c,kx,kyc) 6 KB granules: [plane h/l][r48][ky32], with
// ky swizzle (ky32 ^ 8*((r>>1)&3)) baked in. Layout is global-coalesced:
// one wave's fragment load per mi-plane covers a contiguous permuted 1 KB
// (lane-distinct 16 B chunks).
// r>=36 zeroed. granule index = ((b*3+c)*64 + kx)*2 + kyc.
__global__ __launch_bounds__(256) void prep_weights(
    const float* __restrict__ wk, u16* __restrict__ wa)
{
    int d = blockIdx.x * 256 + threadIdx.x;   // [0, 1536*3072 = 4,718,592)
    int ky32  = d & 31;
    int t1    = d >> 5;
    int r     = t1 % 48;
    int t2    = t1 / 48;
    int plane = t2 & 1;
    int g2    = t2 >> 1;
    int kycp  = g2 & 1;
    int kx    = (g2 >> 1) & 63;
    int bc    = g2 >> 7;
    int c     = bc % 3;
    int b     = bc / 3;
    int ky    = kycp*32 + ky32;
    float v = 0.f;
    if (r < R_) v = wk[(((size_t)(b*R_ + r)*C_ + c)*KS + ky)*KS + kx];
    u16 h = bf16rtn(v);
    u16 o = plane ? bf16rtn(v - bf16tof(h)) : h;
    wa[(size_t)g2*GR + plane*1536 + r*32 + (ky32 ^ (((r >> 1) & 3) << 3))] = o;
}

// Implicit-GEMM conv, MFMA 16x16x32 bf16, 3-product hi/lo split.
// r21 = r19 conv VERBATIM (best verified: 536 us, MfmaUtil 71) + r20's
// float4 tail. R10's B0 cross-STEP prefetch REVERTED (536->551 regression:
// the n==0 selects + extra live state cost more scheduling freedom than the
// ~150cy of hidden ds_read latency bought). Conv scheduling ledger after 10
// rounds: conflicts +1%, sync-removal +2%, issue-reorder +9%, TLP x2 null,
// XCD remap -60%, B-granule pingpong spill, strength-red +2%, B0 -3%.
// This structure is a robust local optimum at ~71% of the 16x16 MFMA pipe.
template<int NT>
__device__ __forceinline__ void conv_body(
    const float* __restrict__ in, const u16* __restrict__ wa,
    float* __restrict__ out, u16* Lh, u16* Ll, int x0, int y0)
{
    const int b    = blockIdx.z;
    const int t    = threadIdx.x;
    const int w    = __builtin_amdgcn_readfirstlane(t >> 6);
    const int lane = t & 63;
    const int nu   = lane & 15;
    const int q    = lane >> 4;

    f32x4 acc[2][3][NT];
    #pragma unroll
    for (int yi = 0; yi < 2; yi++)
        #pragma unroll
        for (int mi = 0; mi < 3; mi++)
            #pragma unroll
            for (int n = 0; n < NT; n++)
                acc[yi][mi][n] = (f32x4){0.f, 0.f, 0.f, 0.f};

    const u16* gbase = wa + (size_t)(b*384)*GR;   // this batch's 384 granules

    // per-lane A-fragment offset within a granule (u16 units); h-plane base.
    // 16B at (mi*16+nu)*32 + ((8q) ^ (((nu>>1)&3)<<3)), l-plane at +1536.
    const int sw   = (8*q) ^ (((nu >> 1) & 3) << 3);
    const int offH = nu*32 + sw;

    bf16x8 A0h[3], A0l[3], A1h[3], A1l[3];

    // prologue: granule 0 -> A0 (in flight across first B staging)
    #pragma unroll
    for (int mi = 0; mi < 3; mi++) {
        A0h[mi] = *(const bf16x8*)(gbase + offH + mi*512);
        A0l[mi] = *(const bf16x8*)(gbase + 1536 + offH + mi*512);
    }

    // A-prefetch walking pointers (granule 1 onward); advance +GR per STEP.
    const u16* aNextH = gbase + GR + offH;
    const u16* aNextL = gbase + GR + 1536 + offH;

// STEP(CB, CH, CL, NH, NL): prefetch next A granule via walking pointers,
// compute current granule with (CH,CL); B base = CB (imm-folded ds offsets).
// B fragments ping-pong one n-block ahead. MFMA order: per n, product-major
// {HH,HL,LH} x (yi,mi) -> same-acc dep distance 6; per-acc accumulation
// order unchanged (HH,HL,LH per granule) -> bit-identical results.
#define STEP(CB, CH, CL, NH, NL) do {                                        \
    _Pragma("unroll")                                                        \
    for (int mi = 0; mi < 3; mi++) {                                         \
        NH[mi] = *(const bf16x8*)(aNextH + mi*512);                          \
        NL[mi] = *(const bf16x8*)(aNextL + mi*512);                          \
    }                                                                        \
    aNextH += GR; aNextL += GR;                                              \
    const u16* cb_ = (CB);                                                   \
    bf16x8 Bh_[2][2], Bl_[2][2];                                             \
    _Pragma("unroll")                                                        \
    for (int yi = 0; yi < 2; yi++) {                                         \
        const u16* p0_ = cb_ + 32*yi;                                        \
        Bh_[0][yi] = *(const bf16x8*)p0_;                                    \
        Bl_[0][yi] = *(const bf16x8*)(p0_ + (size_t)LCOLS*PITCH);            \
    }                                                                        \
    _Pragma("unroll")                                                        \
    for (int n = 0; n < NT; n++) {                                           \
        if (n + 1 < NT) {                                                    \
            _Pragma("unroll")                                                \
            for (int yi = 0; yi < 2; yi++) {                                 \
                const u16* pn_ = cb_ + (n+1)*16*PITCH + 32*yi;               \
                Bh_[(n+1)&1][yi] = *(const bf16x8*)pn_;                      \
                Bl_[(n+1)&1][yi] = *(const bf16x8*)(pn_ + (size_t)LCOLS*PITCH); \
            }                                                                \
        }                                                                    \
        _Pragma("unroll")                                                    \
        for (int yi = 0; yi < 2; yi++)                                       \
            _Pragma("unroll")                                                \
            for (int mi = 0; mi < 3; mi++)                                   \
                acc[yi][mi][n] = __builtin_amdgcn_mfma_f32_16x16x32_bf16(CH[mi], Bh_[n&1][yi], acc[yi][mi][n], 0, 0, 0); \
        _Pragma("unroll")                                                    \
        for (int yi = 0; yi < 2; yi++)                                       \
            _Pragma("unroll")                                                \
            for (int mi = 0; mi < 3; mi++)                                   \
                acc[yi][mi][n] = __builtin_amdgcn_mfma_f32_16x16x32_bf16(CH[mi], Bl_[n&1][yi], acc[yi][mi][n], 0, 0, 0); \
        _Pragma("unroll")                                                    \
        for (int yi = 0; yi < 2; yi++)                                       \
            _Pragma("unroll")                                                \
            for (int mi = 0; mi < 3; mi++)                                   \
                acc[yi][mi][n] = __builtin_amdgcn_mfma_f32_16x16x32_bf16(CL[mi], Bh_[n&1][yi], acc[yi][mi][n], 0, 0, 0); \
    }                                                                        \
} while (0)

    for (int c = 0; c < C_; c++) {
        __syncthreads();
        // ---- stage B rows y0..y0+119, cols x0..x0+127, transposed + split ----
        // 60 row-pairs x 32 float4-cols = 1920 items over 256 threads (8 iters).
        // Row-pair staggered by col-block octet ((a>>3)&3): store banks are
        // (lane&1, (lane>>3)&3) -> 8 banks x 4-way; global loads stay coalesced
        // in 128 B segments (row uniform per 8 lanes).
        const float* src = in + ((size_t)(b*C_ + c))*H_*W_;
        #pragma unroll
        for (int k = 0; k < 8; k++) {
            int idx = t + 256*k;
            if (idx < 1920) {
                int a    = idx & 31;         // col-block 0..31
                int pr   = (idx >> 5) + ((a >> 3) & 3);
                if (pr >= 60) pr -= 60;      // row-pair 0..59 (bijection per a)
                int r0   = pr * 2;
                int c4   = a * 4;
                int gx   = x0 + c4;
                int gy   = y0 + r0;
                float4 va = make_float4(0.f,0.f,0.f,0.f), vb = va;
                if (gx < W_) {               // float4 chunks entirely in or out
                    if (gy < H_)     va = *(const float4*)(src + (size_t)gy*W_ + gx);
                    if (gy + 1 < H_) vb = *(const float4*)(src + (size_t)(gy+1)*W_ + gx);
                }
                const float* pa = &va.x;
                const float* pb = &vb.x;
                #pragma unroll
                for (int j = 0; j < 4; j++) {
                    int col = c4 + j;
                    u16 ha = bf16rtn(pa[j]);
                    u16 hb = bf16rtn(pb[j]);
                    u16 la = bf16rtn(pa[j] - bf16tof(ha));
                    u16 lb = bf16rtn(pb[j] - bf16tof(hb));
                    *(unsigned*)&Lh[col*PITCH + r0] = (unsigned)ha | ((unsigned)hb << 16);
                    *(unsigned*)&Ll[col*PITCH + r0] = (unsigned)la | ((unsigned)lb << 16);
                }
            }
        }
        __syncthreads();

        // ---- granule loop, barrier-free: A ping-pong; B base walks +PITCH ----
        const u16* cbP = Lh + (size_t)nu*PITCH + 8*q + 8*w;   // kx=0, kycp=0
        #pragma unroll 1
        for (int gi2 = 0; gi2 < 128; gi2 += 2) {
            STEP(cbP,      A0h, A0l, A1h, A1l);
            STEP(cbP + 32, A1h, A1l, A0h, A0l);
            cbP += PITCH;
        }
    }
#undef STEP

    // ---- direct epilogue: wave owns its 2 y's; coalesced stores ----
    #pragma unroll
    for (int yi = 0; yi < 2; yi++) {
        const int y = y0 + 8*w + 32*yi;
        if (y <= 320) {
            #pragma unroll
            for (int mi = 0; mi < 3; mi++) {
                #pragma unroll
                for (int n = 0; n < NT; n++) {
                    #pragma unroll
                    for (int i = 0; i < 4; i++) {
                        int r = mi*16 + q*4 + i;     // C/D: row = (lane>>4)*4 + reg
                        int x = x0 + n*16 + nu;      //      col = lane&15
                        if (r < R_ && x < OX)
                            out[((size_t)(b*R_ + r)*OY + y)*OX + x] = acc[yi][mi][n][i];
                    }
                }
            }
        }
    }
}

__global__ __launch_bounds__(256, 2) void conv_mfma(
    const float* __restrict__ in, const u16* __restrict__ wa, float* __restrict__ out)
{
    // B only: 2 x 128*120 u16 = 61440 B -> 2 WG/CU (A streams via regs).
    // launch_bounds(256,2): pin 2 waves/SIMD so regalloc can't cost occupancy.
    __shared__ __align__(16) u16 smem[2*LCOLS*PITCH];
    u16* Lh = smem;
    u16* Ll = smem + LCOLS*PITCH;
    // y mapping: s<40 -> y0 = 64*(s>>3) + (s&7); waves cover y0 + {8w, 8w+32}
    // = all 8 residues in a 64-row block. s==40 -> y0=320 (only w=0,yi=0 valid).
    const int s  = blockIdx.y;
    const int y0 = (s < 40) ? ((s >> 3)*64 + (s & 7)) : 320;

    if (blockIdx.x == 0)      conv_body<4>(in, wa, out, Lh, Ll, 0,   y0);
    else if (blockIdx.x == 1) conv_body<4>(in, wa, out, Lh, Ll, 64,  y0);
    else                      conv_body<3>(in, wa, out, Lh, Ll, 128, y0);
}

// Bilinear resize (iy==i, ix==j for the needed range) + per-block max partials.
__global__ __launch_bounds__(256) void resize_kernel(
    const float* __restrict__ cv, float* __restrict__ out, float* __restrict__ pmax)
{
    const int t = threadIdx.x;
    const int idx = blockIdx.x * 256 + t;
    const int j = idx % WC;
    const int rest = idx / WC;
    const int i = rest % HC;
    const int br = rest / HC;

    float fy = (i + 32.5f) * (1.0f/384.0f);
    float fx = (j + 32.5f) * (1.0f/224.0f);

    const float* p = cv + ((size_t)br*OY + i)*OX + j;
    float v00 = p[0], v01 = p[1], v10 = p[OX], v11 = p[OX+1];
    float v = (1.f-fy)*((1.f-fx)*v00 + fx*v01) + fy*((1.f-fx)*v10 + fx*v11);
    out[idx] = v;

    __shared__ float sm[4];
    float m = wave_max(v);
    if ((t & 63) == 0) sm[t >> 6] = m;
    __syncthreads();
    if (t == 0) pmax[blockIdx.x] = fmaxf(fmaxf(sm[0], sm[1]), fmaxf(sm[2], sm[3]));
}

__global__ __launch_bounds__(256) void reduce_kernel(
    const float* __restrict__ part, float* __restrict__ res, int n, int is_sum)
{
    const int b = blockIdx.x;
    const int t = threadIdx.x;
    const float* p = part + (size_t)b*n;
    float v = is_sum ? 0.f : -3.0e38f;
    for (int k = t; k < n; k += 256) v = is_sum ? (v + p[k]) : fmaxf(v, p[k]);
    __shared__ float sm[4];
    float w = is_sum ? wave_sum(v) : wave_max(v);
    if ((t & 63) == 0) sm[t >> 6] = w;
    __syncthreads();
    if (t == 0) {
        res[b] = is_sum ? (sm[0]+sm[1]+sm[2]+sm[3])
                        : fmaxf(fmaxf(sm[0], sm[1]), fmaxf(sm[2], sm[3]));
    }
}

// float4 exp: 1024 elems/block (grid 7200), per-block partial sum.
__global__ __launch_bounds__(256) void exp_kernel(
    float* __restrict__ out, const float* __restrict__ bmax, float* __restrict__ psum)
{
    const int t = threadIdx.x;
    const int base = blockIdx.x * 1024 + t * 4;
    const int b = blockIdx.x / EXP_BLKS_PER_BATCH;
    const float m = bmax[b];
    float4 v = *(float4*)(out + base);
    v.x = expf(v.x - m); v.y = expf(v.y - m);
    v.z = expf(v.z - m); v.w = expf(v.w - m);
    *(float4*)(out + base) = v;
    __shared__ float sm[4];
    float s = wave_sum(v.x + v.y + v.z + v.w);
    if ((t & 63) == 0) sm[t >> 6] = s;
    __syncthreads();
    if (t == 0) psum[blockIdx.x] = sm[0]+sm[1]+sm[2]+sm[3];
}

// float4 scale: 1024 elems/block (grid 7200).
__global__ __launch_bounds__(256) void scale_kernel(
    float* __restrict__ out, const float* __restrict__ bsum)
{
    const int base = blockIdx.x * 1024 + threadIdx.x * 4;
    const int b = blockIdx.x / EXP_BLKS_PER_BATCH;
    const float d = bsum[b];
    float4 v = *(float4*)(out + base);
    v.x = v.x / d; v.y = v.y / d; v.z = v.z / d; v.w = v.w / d;
    *(float4*)(out + base) = v;
}

extern "C" void kernel_launch(void* const* d_in, const int* in_sizes, int n_in,
                              void* d_out, int out_size, void* d_ws, size_t ws_size,
                              hipStream_t stream)
{
    const float* logits = (const float*)d_in[0];   // (4,3,384,224) fp32
    const float* wk     = (const float*)d_in[1];   // (144,3,64,64) fp32
    float* out = (float*)d_out;                    // (4,36,320,160) fp32
    char*  wsB = (char*)d_ws;

    // workspace layout (bytes)
    float* convOut = (float*)wsB;                              // 29,768,256 B
    u16*   wa      = (u16*)(wsB + 29768256);                   // 9,437,184 B
    float* pmax    = (float*)(wsB + 29768256 + 9437184);       // 28800 f32
    float* psum    = pmax + 28800;                             // 7200 f32 used
    float* bmax    = psum + 28800;
    float* bsum    = bmax + 8;

    hipLaunchKernelGGL(prep_weights, dim3(18432), dim3(256), 0, stream, wk, wa);
    hipLaunchKernelGGL(conv_mfma,    dim3(3, 41, B_), dim3(256), 0, stream, logits, wa, convOut);
    hipLaunchKernelGGL(resize_kernel, dim3(28800), dim3(256), 0, stream, convOut, out, pmax);
    hipLaunchKernelGGL(reduce_kernel, dim3(4),     dim3(256), 0, stream, pmax, bmax, BLKS_PER_BATCH, 0);
    hipLaunchKernelGGL(exp_kernel,    dim3(7200),  dim3(256), 0, stream, out, bmax, psum);
    hipLaunchKernelGGL(reduce_kernel, dim3(4),     dim3(256), 0, stream, psum, bsum, EXP_BLKS_PER_BATCH, 1);
    hipLaunchKernelGGL(scale_kernel,  dim3(7200),  dim3(256), 0, stream, out, bsum);
}

// Round 12
// 606.909 us; speedup vs baseline: 1.0187x; 1.0187x over previous
//
#include <hip/hip_runtime.h>

typedef short bf16x8 __attribute__((ext_vector_type(8)));
typedef float f32x4  __attribute__((ext_vector_type(4)));
typedef unsigned short u16;

#define B_ 4
#define R_ 36
#define RP 48          // r padded to 3 m-tiles of 16
#define C_ 3
#define H_ 384
#define W_ 224
#define KS 64
#define OY 321         // conv-out rows needed
#define OX 161         // conv-out cols needed
#define HC 320
#define WC 160
#define LCOLS 128      // staged cols per WG
#define PITCH 120      // B rows per col: 64 + 56 (waves at 8w, +32 for 2nd y)
#define GR 3072        // u16 per A-granule: 2 planes x 48 r x 32 ky (6 KB)
#define BLKS_PER_BATCH 7200
#define EXP_BLKS_PER_BATCH 1800   // float4 tail: 1024 elems/block

__device__ __forceinline__ u16 bf16rtn(float v) {
    union { float f; unsigned u; } U; U.f = v;
    unsigned r = U.u + 0x7fffu + ((U.u >> 16) & 1u);
    return (u16)(r >> 16);
}
__device__ __forceinline__ float bf16tof(u16 h) {
    union { float f; unsigned u; } U; U.u = ((unsigned)h) << 16; return U.f;
}

__device__ __forceinline__ float wave_max(float v) {
    #pragma unroll
    for (int off = 32; off > 0; off >>= 1) v = fmaxf(v, __shfl_down(v, off, 64));
    return v;
}
__device__ __forceinline__ float wave_sum(float v) {
    #pragma unroll
    for (int off = 32; off > 0; off >>= 1) v += __shfl_down(v, off, 64);
    return v;
}

// Weights -> per-(b,c,kx,kyc) 6 KB granules: [plane h/l][r48][ky32], with
// ky swizzle (ky32 ^ 8*((r>>1)&3)) baked in. Layout is global-coalesced:
// one wave's fragment load per mi-plane covers a contiguous permuted 1 KB
// (lane-distinct 16 B chunks).
// r>=36 zeroed. granule index = ((b*3+c)*64 + kx)*2 + kyc.
__global__ __launch_bounds__(256) void prep_weights(
    const float* __restrict__ wk, u16* __restrict__ wa)
{
    int d = blockIdx.x * 256 + threadIdx.x;   // [0, 1536*3072 = 4,718,592)
    int ky32  = d & 31;
    int t1    = d >> 5;
    int r     = t1 % 48;
    int t2    = t1 / 48;
    int plane = t2 & 1;
    int g2    = t2 >> 1;
    int kycp  = g2 & 1;
    int kx    = (g2 >> 1) & 63;
    int bc    = g2 >> 7;
    int c     = bc % 3;
    int b     = bc / 3;
    int ky    = kycp*32 + ky32;
    float v = 0.f;
    if (r < R_) v = wk[(((size_t)(b*R_ + r)*C_ + c)*KS + ky)*KS + kx];
    u16 h = bf16rtn(v);
    u16 o = plane ? bf16rtn(v - bf16tof(h)) : h;
    wa[(size_t)g2*GR + plane*1536 + r*32 + (ky32 ^ (((r >> 1) & 3) << 3))] = o;
}

// Implicit-GEMM conv, MFMA 16x16x32 bf16, 3-product hi/lo split.
// r22 = r19 conv + s_setprio(1) around each n-block's 18-MFMA product
// cluster (T5). Regime justification: the granule loop is barrier-free, so
// the 8 CU-resident waves drift out of phase -> at any instant some waves
// issue ds_reads while others enter MFMA clusters; setprio biases the CU
// scheduler toward MFMA-entering waves (the catalog's role-diversity gate,
// which the prior 512-thread setprio exposure confounded). Prio drops to 0
// during the B-prefetch reads. Zero register/math change -> bit-identical.
// Cycle model (R11): window 3425 cy = MFMA 2560 (75%) + exposed LDS ~865;
// target is the exposed slice. Null here => structural roofline.
template<int NT>
__device__ __forceinline__ void conv_body(
    const float* __restrict__ in, const u16* __restrict__ wa,
    float* __restrict__ out, u16* Lh, u16* Ll, int x0, int y0)
{
    const int b    = blockIdx.z;
    const int t    = threadIdx.x;
    const int w    = __builtin_amdgcn_readfirstlane(t >> 6);
    const int lane = t & 63;
    const int nu   = lane & 15;
    const int q    = lane >> 4;

    f32x4 acc[2][3][NT];
    #pragma unroll
    for (int yi = 0; yi < 2; yi++)
        #pragma unroll
        for (int mi = 0; mi < 3; mi++)
            #pragma unroll
            for (int n = 0; n < NT; n++)
                acc[yi][mi][n] = (f32x4){0.f, 0.f, 0.f, 0.f};

    const u16* gbase = wa + (size_t)(b*384)*GR;   // this batch's 384 granules

    // per-lane A-fragment offset within a granule (u16 units); h-plane base.
    // 16B at (mi*16+nu)*32 + ((8q) ^ (((nu>>1)&3)<<3)), l-plane at +1536.
    const int sw   = (8*q) ^ (((nu >> 1) & 3) << 3);
    const int offH = nu*32 + sw;

    bf16x8 A0h[3], A0l[3], A1h[3], A1l[3];

    // prologue: granule 0 -> A0 (in flight across first B staging)
    #pragma unroll
    for (int mi = 0; mi < 3; mi++) {
        A0h[mi] = *(const bf16x8*)(gbase + offH + mi*512);
        A0l[mi] = *(const bf16x8*)(gbase + 1536 + offH + mi*512);
    }

    // A-prefetch walking pointers (granule 1 onward); advance +GR per STEP.
    const u16* aNextH = gbase + GR + offH;
    const u16* aNextL = gbase + GR + 1536 + offH;

// STEP(CB, CH, CL, NH, NL): prefetch next A granule via walking pointers,
// compute current granule with (CH,CL); B base = CB (imm-folded ds offsets).
// B fragments ping-pong one n-block ahead. MFMA order: per n, product-major
// {HH,HL,LH} x (yi,mi) -> same-acc dep distance 6; per-acc accumulation
// order unchanged (HH,HL,LH per granule) -> bit-identical results.
// setprio(1) wraps the 18-MFMA cluster; 0 during the B-prefetch reads.
#define STEP(CB, CH, CL, NH, NL) do {                                        \
    _Pragma("unroll")                                                        \
    for (int mi = 0; mi < 3; mi++) {                                         \
        NH[mi] = *(const bf16x8*)(aNextH + mi*512);                          \
        NL[mi] = *(const bf16x8*)(aNextL + mi*512);                          \
    }                                                                        \
    aNextH += GR; aNextL += GR;                                              \
    const u16* cb_ = (CB);                                                   \
    bf16x8 Bh_[2][2], Bl_[2][2];                                             \
    _Pragma("unroll")                                                        \
    for (int yi = 0; yi < 2; yi++) {                                         \
        const u16* p0_ = cb_ + 32*yi;                                        \
        Bh_[0][yi] = *(const bf16x8*)p0_;                                    \
        Bl_[0][yi] = *(const bf16x8*)(p0_ + (size_t)LCOLS*PITCH);            \
    }                                                                        \
    _Pragma("unroll")                                                        \
    for (int n = 0; n < NT; n++) {                                           \
        if (n + 1 < NT) {                                                    \
            _Pragma("unroll")                                                \
            for (int yi = 0; yi < 2; yi++) {                                 \
                const u16* pn_ = cb_ + (n+1)*16*PITCH + 32*yi;               \
                Bh_[(n+1)&1][yi] = *(const bf16x8*)pn_;                      \
                Bl_[(n+1)&1][yi] = *(const bf16x8*)(pn_ + (size_t)LCOLS*PITCH); \
            }                                                                \
        }                                                                    \
        __builtin_amdgcn_s_setprio(1);                                       \
        _Pragma("unroll")                                                    \
        for (int yi = 0; yi < 2; yi++)                                       \
            _Pragma("unroll")                                                \
            for (int mi = 0; mi < 3; mi++)                                   \
                acc[yi][mi][n] = __builtin_amdgcn_mfma_f32_16x16x32_bf16(CH[mi], Bh_[n&1][yi], acc[yi][mi][n], 0, 0, 0); \
        _Pragma("unroll")                                                    \
        for (int yi = 0; yi < 2; yi++)                                       \
            _Pragma("unroll")                                                \
            for (int mi = 0; mi < 3; mi++)                                   \
                acc[yi][mi][n] = __builtin_amdgcn_mfma_f32_16x16x32_bf16(CH[mi], Bl_[n&1][yi], acc[yi][mi][n], 0, 0, 0); \
        _Pragma("unroll")                                                    \
        for (int yi = 0; yi < 2; yi++)                                       \
            _Pragma("unroll")                                                \
            for (int mi = 0; mi < 3; mi++)                                   \
                acc[yi][mi][n] = __builtin_amdgcn_mfma_f32_16x16x32_bf16(CL[mi], Bh_[n&1][yi], acc[yi][mi][n], 0, 0, 0); \
        __builtin_amdgcn_s_setprio(0);                                       \
    }                                                                        \
} while (0)

    for (int c = 0; c < C_; c++) {
        __syncthreads();
        // ---- stage B rows y0..y0+119, cols x0..x0+127, transposed + split ----
        // 60 row-pairs x 32 float4-cols = 1920 items over 256 threads (8 iters).
        // Row-pair staggered by col-block octet ((a>>3)&3): store banks are
        // (lane&1, (lane>>3)&3) -> 8 banks x 4-way; global loads stay coalesced
        // in 128 B segments (row uniform per 8 lanes).
        const float* src = in + ((size_t)(b*C_ + c))*H_*W_;
        #pragma unroll
        for (int k = 0; k < 8; k++) {
            int idx = t + 256*k;
            if (idx < 1920) {
                int a    = idx & 31;         // col-block 0..31
                int pr   = (idx >> 5) + ((a >> 3) & 3);
                if (pr >= 60) pr -= 60;      // row-pair 0..59 (bijection per a)
                int r0   = pr * 2;
                int c4   = a * 4;
                int gx   = x0 + c4;
                int gy   = y0 + r0;
                float4 va = make_float4(0.f,0.f,0.f,0.f), vb = va;
                if (gx < W_) {               // float4 chunks entirely in or out
                    if (gy < H_)     va = *(const float4*)(src + (size_t)gy*W_ + gx);
                    if (gy + 1 < H_) vb = *(const float4*)(src + (size_t)(gy+1)*W_ + gx);
                }
                const float* pa = &va.x;
                const float* pb = &vb.x;
                #pragma unroll
                for (int j = 0; j < 4; j++) {
                    int col = c4 + j;
                    u16 ha = bf16rtn(pa[j]);
                    u16 hb = bf16rtn(pb[j]);
                    u16 la = bf16rtn(pa[j] - bf16tof(ha));
                    u16 lb = bf16rtn(pb[j] - bf16tof(hb));
                    *(unsigned*)&Lh[col*PITCH + r0] = (unsigned)ha | ((unsigned)hb << 16);
                    *(unsigned*)&Ll[col*PITCH + r0] = (unsigned)la | ((unsigned)lb << 16);
                }
            }
        }
        __syncthreads();

        // ---- granule loop, barrier-free: A ping-pong; B base walks +PITCH ----
        const u16* cbP = Lh + (size_t)nu*PITCH + 8*q + 8*w;   // kx=0, kycp=0
        #pragma unroll 1
        for (int gi2 = 0; gi2 < 128; gi2 += 2) {
            STEP(cbP,      A0h, A0l, A1h, A1l);
            STEP(cbP + 32, A1h, A1l, A0h, A0l);
            cbP += PITCH;
        }
    }
#undef STEP

    // ---- direct epilogue: wave owns its 2 y's; coalesced stores ----
    #pragma unroll
    for (int yi = 0; yi < 2; yi++) {
        const int y = y0 + 8*w + 32*yi;
        if (y <= 320) {
            #pragma unroll
            for (int mi = 0; mi < 3; mi++) {
                #pragma unroll
                for (int n = 0; n < NT; n++) {
                    #pragma unroll
                    for (int i = 0; i < 4; i++) {
                        int r = mi*16 + q*4 + i;     // C/D: row = (lane>>4)*4 + reg
                        int x = x0 + n*16 + nu;      //      col = lane&15
                        if (r < R_ && x < OX)
                            out[((size_t)(b*R_ + r)*OY + y)*OX + x] = acc[yi][mi][n][i];
                    }
                }
            }
        }
    }
}

__global__ __launch_bounds__(256, 2) void conv_mfma(
    const float* __restrict__ in, const u16* __restrict__ wa, float* __restrict__ out)
{
    // B only: 2 x 128*120 u16 = 61440 B -> 2 WG/CU (A streams via regs).
    // launch_bounds(256,2): pin 2 waves/SIMD so regalloc can't cost occupancy.
    __shared__ __align__(16) u16 smem[2*LCOLS*PITCH];
    u16* Lh = smem;
    u16* Ll = smem + LCOLS*PITCH;
    // y mapping: s<40 -> y0 = 64*(s>>3) + (s&7); waves cover y0 + {8w, 8w+32}
    // = all 8 residues in a 64-row block. s==40 -> y0=320 (only w=0,yi=0 valid).
    const int s  = blockIdx.y;
    const int y0 = (s < 40) ? ((s >> 3)*64 + (s & 7)) : 320;

    if (blockIdx.x == 0)      conv_body<4>(in, wa, out, Lh, Ll, 0,   y0);
    else if (blockIdx.x == 1) conv_body<4>(in, wa, out, Lh, Ll, 64,  y0);
    else                      conv_body<3>(in, wa, out, Lh, Ll, 128, y0);
}

// Bilinear resize (iy==i, ix==j for the needed range) + per-block max partials.
__global__ __launch_bounds__(256) void resize_kernel(
    const float* __restrict__ cv, float* __restrict__ out, float* __restrict__ pmax)
{
    const int t = threadIdx.x;
    const int idx = blockIdx.x * 256 + t;
    const int j = idx % WC;
    const int rest = idx / WC;
    const int i = rest % HC;
    const int br = rest / HC;

    float fy = (i + 32.5f) * (1.0f/384.0f);
    float fx = (j + 32.5f) * (1.0f/224.0f);

    const float* p = cv + ((size_t)br*OY + i)*OX + j;
    float v00 = p[0], v01 = p[1], v10 = p[OX], v11 = p[OX+1];
    float v = (1.f-fy)*((1.f-fx)*v00 + fx*v01) + fy*((1.f-fx)*v10 + fx*v11);
    out[idx] = v;

    __shared__ float sm[4];
    float m = wave_max(v);
    if ((t & 63) == 0) sm[t >> 6] = m;
    __syncthreads();
    if (t == 0) pmax[blockIdx.x] = fmaxf(fmaxf(sm[0], sm[1]), fmaxf(sm[2], sm[3]));
}

__global__ __launch_bounds__(256) void reduce_kernel(
    const float* __restrict__ part, float* __restrict__ res, int n, int is_sum)
{
    const int b = blockIdx.x;
    const int t = threadIdx.x;
    const float* p = part + (size_t)b*n;
    float v = is_sum ? 0.f : -3.0e38f;
    for (int k = t; k < n; k += 256) v = is_sum ? (v + p[k]) : fmaxf(v, p[k]);
    __shared__ float sm[4];
    float w = is_sum ? wave_sum(v) : wave_max(v);
    if ((t & 63) == 0) sm[t >> 6] = w;
    __syncthreads();
    if (t == 0) {
        res[b] = is_sum ? (sm[0]+sm[1]+sm[2]+sm[3])
                        : fmaxf(fmaxf(sm[0], sm[1]), fmaxf(sm[2], sm[3]));
    }
}

// float4 exp: 1024 elems/block (grid 7200), per-block partial sum.
__global__ __launch_bounds__(256) void exp_kernel(
    float* __restrict__ out, const float* __restrict__ bmax, float* __restrict__ psum)
{
    const int t = threadIdx.x;
    const int base = blockIdx.x * 1024 + t * 4;
    const int b = blockIdx.x / EXP_BLKS_PER_BATCH;
    const float m = bmax[b];
    float4 v = *(float4*)(out + base);
    v.x = expf(v.x - m); v.y = expf(v.y - m);
    v.z = expf(v.z - m); v.w = expf(v.w - m);
    *(float4*)(out + base) = v;
    __shared__ float sm[4];
    float s = wave_sum(v.x + v.y + v.z + v.w);
    if ((t & 63) == 0) sm[t >> 6] = s;
    __syncthreads();
    if (t == 0) psum[blockIdx.x] = sm[0]+sm[1]+sm[2]+sm[3];
}

// float4 scale: 1024 elems/block (grid 7200).
__global__ __launch_bounds__(256) void scale_kernel(
    float* __restrict__ out, const float* __restrict__ bsum)
{
    const int base = blockIdx.x * 1024 + threadIdx.x * 4;
    const int b = blockIdx.x / EXP_BLKS_PER_BATCH;
    const float d = bsum[b];
    float4 v = *(float4*)(out + base);
    v.x = v.x / d; v.y = v.y / d; v.z = v.z / d; v.w = v.w / d;
    *(float4*)(out + base) = v;
}

extern "C" void kernel_launch(void* const* d_in, const int* in_sizes, int n_in,
                              void* d_out, int out_size, void* d_ws, size_t ws_size,
                              hipStream_t stream)
{
    const float* logits = (const float*)d_in[0];   // (4,3,384,224) fp32
    const float* wk     = (const float*)d_in[1];   // (144,3,64,64) fp32
    float* out = (float*)d_out;                    // (4,36,320,160) fp32
    char*  wsB = (char*)d_ws;

    // workspace layout (bytes)
    float* convOut = (float*)wsB;                              // 29,768,256 B
    u16*   wa      = (u16*)(wsB + 29768256);                   // 9,437,184 B
    float* pmax    = (float*)(wsB + 29768256 + 9437184);       // 28800 f32
    float* psum    = pmax + 28800;                             // 7200 f32 used
    float* bmax    = psum + 28800;
    float* bsum    = bmax + 8;

    hipLaunchKernelGGL(prep_weights, dim3(18432), dim3(256), 0, stream, wk, wa);
    hipLaunchKernelGGL(conv_mfma,    dim3(3, 41, B_), dim3(256), 0, stream, logits, wa, convOut);
    hipLaunchKernelGGL(resize_kernel, dim3(28800), dim3(256), 0, stream, convOut, out, pmax);
    hipLaunchKernelGGL(reduce_kernel, dim3(4),     dim3(256), 0, stream, pmax, bmax, BLKS_PER_BATCH, 0);
    hipLaunchKernelGGL(exp_kernel,    dim3(7200),  dim3(256), 0, stream, out, bmax, psum);
    hipLaunchKernelGGL(reduce_kernel, dim3(4),     dim3(256), 0, stream, psum, bsum, EXP_BLKS_PER_BATCH, 1);
    hipLaunchKernelGGL(scale_kernel,  dim3(7200),  dim3(256), 0, stream, out, bsum);
}